// Round 1
// baseline (434.871 us; speedup 1.0000x reference)
//
#include <hip/hip_runtime.h>

// SIREN INR MLP — numpy-float32 emulation, packed-fp32.
// R7 (PASS 443us): L0/L1 numpy-exact tree, L2/L3 fma-chain, rintf sin.
// R8: +magic-bit quadrant extraction (PROVEN bit-exact: absmax unchanged)
//     +launch_bounds(256,8) -> VGPR capped 32 -> scratch spills, 3.1GB HBM, 830us.
// R9 (PASS 435.4us) = R8's sin + R7's launch bounds (VGPR ~52, no spills).
// R10: resubmit of R9 verbatim — previous round's bench was an infra failure
//  (container acquisition), no counters captured. Op-census model says R9 sits
//  at ~98.6% of the achievable VALU roofline (5360 scalar-equiv lane-ops/thread
//  x 2cyc x 64 waves/SIMD = 686k cyc; at m07's sustained ~1.6GHz VALU clock
//  => 429us predicted vs 435us measured). Need counters to confirm:
//  expect VALUBusy>=90%, MfmaUtil 0, HBM ~3% peak, 0 bank conflicts.

typedef float v2f __attribute__((ext_vector_type(2)));

static constexpr int PW = 921;
static constexpr float MAGIC = 12582912.0f;   // 1.5 * 2^23

__device__ __forceinline__ v2f fma2(v2f a, v2f b, v2f c) {
    return __builtin_elementwise_fma(a, b, c);
}
__device__ __forceinline__ v2f splat2(float x) { v2f r; r.x = x; r.y = x; return r; }

// numpy SIMD f32 sin, 2 points packed (bit-exact config verified in R8).
__device__ __forceinline__ v2f np_sinf2(v2f x) {
#pragma clang fp contract(off)
    v2f t = x * splat2(0x1.45f306p-1f);
    v2f qf; qf.x = __builtin_rintf(t.x); qf.y = __builtin_rintf(t.y);
    const unsigned mx = __builtin_bit_cast(unsigned, __fadd_rn(qf.x, MAGIC));
    const unsigned my = __builtin_bit_cast(unsigned, __fadd_rn(qf.y, MAGIC));
    v2f r = fma2(qf, splat2(-0x1.921fb0p+0f), x);
    r = fma2(qf, splat2(-0x1.5110b4p-22f), r);
    r = fma2(qf, splat2(-0x1.846988p-48f), r);
    v2f r2 = r * r;
    v2f ys = fma2(splat2(0x1.5e9e9cp-19f), r2, splat2(-0x1.a06bbap-13f));
    ys = fma2(ys, r2, splat2(0x1.11119ap-7f));
    ys = fma2(ys, r2, splat2(-0x1.555556p-3f));
    ys = ys * r2;
    ys = fma2(ys, r, r);
    v2f yc = fma2(splat2(0x1.98e616p-16f), r2, splat2(-0x1.6c06dcp-10f));
    yc = fma2(yc, r2, splat2(0x1.55553cp-5f));
    yc = fma2(yc, r2, splat2(-0.5f));
    yc = fma2(yc, r2, splat2(1.0f));
    float rx = (mx & 1u) ? yc.x : ys.x;
    float ry = (my & 1u) ? yc.y : ys.y;
    const unsigned sx = (mx & 2u) << 30;   // q&2 -> sign bit
    const unsigned sy = (my & 2u) << 30;
    v2f res;
    res.x = __builtin_bit_cast(float, __builtin_bit_cast(unsigned, rx) ^ sx);
    res.y = __builtin_bit_cast(float, __builtin_bit_cast(unsigned, ry) ^ sy);
    return res;
}

// numpy einsum contig_contig_outstride0_two tree (exact) — L1.
__device__ __forceinline__ v2f np_dot20_2(const float* __restrict__ w,
                                          const v2f* h) {
#pragma clang fp contract(off)
    v2f s[4];
#pragma unroll
    for (int j = 0; j < 4; ++j) {
        v2f p0  = h[j]      * splat2(w[j]);
        v2f p4  = h[4 + j]  * splat2(w[4 + j]);
        v2f p8  = h[8 + j]  * splat2(w[8 + j]);
        v2f p12 = h[12 + j] * splat2(w[12 + j]);
        v2f p16 = h[16 + j] * splat2(w[16 + j]);
        v2f t = p8 + p12;
        t = p4 + t;
        t = p0 + t;
        s[j] = p16 + t;
    }
    return (s[0] + s[1]) + (s[2] + s[3]);
}

// FMA-chain dot (bias-initialized) — L2/L3 only (bounded amplification).
__device__ __forceinline__ v2f fma_dot20(const float* __restrict__ w,
                                         const v2f* h, float bias) {
#pragma clang fp contract(off)
    v2f acc = splat2(bias);
#pragma unroll
    for (int i = 0; i < 20; ++i)
        acc = fma2(splat2(w[i]), h[i], acc);
    return acc;
}

__global__ void __launch_bounds__(256)
siren_mlp(const float* __restrict__ coords,
          const float* __restrict__ weights,
          float* __restrict__ out, int N)
{
#pragma clang fp contract(off)
    const int b = blockIdx.y;
    const float* __restrict__ w = weights + b * PW;  // wave-uniform -> s_load
    const int n0 = blockIdx.x * 512 + threadIdx.x;
    const int n1 = n0 + 256;
    const size_t base = (size_t)b * N;

    const float2* __restrict__ cp = (const float2*)coords;
    const float2 c0 = cp[base + n0];
    const float2 c1 = cp[base + n1];
    v2f X; X.x = c0.x; X.y = c1.x;
    v2f Y; Y.x = c0.y; Y.y = c1.y;

    v2f h[20], g[20];

    // ---- layer 0: 2 -> 20. (x*w0)+(y*w1), +b, *20 — numpy-exact, no fma.
#pragma unroll
    for (int o = 0; o < 20; ++o) {
        v2f z = (X * splat2(w[2 * o])) + (Y * splat2(w[2 * o + 1]));
        z = z + splat2(w[40 + o]);
        h[o] = np_sinf2(splat2(20.0f) * z);
    }

    // ---- layer 1: 20 -> 20 — numpy-exact tree.
#pragma unroll
    for (int o = 0; o < 20; ++o) {
        v2f z = np_dot20_2(w + 60 + 20 * o, h) + splat2(w[460 + o]);
        g[o] = np_sinf2(splat2(20.0f) * z);
    }

    // ---- layer 2: 20 -> 20 — fma chain.
#pragma unroll
    for (int o = 0; o < 20; ++o) {
        v2f z = fma_dot20(w + 480 + 20 * o, g, w[880 + o]);
        h[o] = np_sinf2(splat2(20.0f) * z);
    }

    // ---- layer 3: 20 -> 1, clip[0,1] — fma chain, packed clamp.
    {
        v2f z = fma_dot20(w + 900, h, w[920]);
        z = __builtin_elementwise_max(z, splat2(0.0f));
        z = __builtin_elementwise_min(z, splat2(1.0f));
        out[base + n0] = z.x;
        out[base + n1] = z.y;
    }
}

extern "C" void kernel_launch(void* const* d_in, const int* in_sizes, int n_in,
                              void* d_out, int out_size, void* d_ws, size_t ws_size,
                              hipStream_t stream) {
    const float* coords  = (const float*)d_in[0];
    const float* weights = (const float*)d_in[1];
    float* out = (float*)d_out;

    const int B = in_sizes[1] / PW;            // 128
    const int N = in_sizes[0] / (2 * B);       // 65536

    dim3 grid(N / 512, B);
    siren_mlp<<<grid, dim3(256), 0, stream>>>(coords, weights, out, N);
}

// Round 2
// 400.879 us; speedup vs baseline: 1.0848x; 1.0848x over previous
//
#include <hip/hip_runtime.h>

// SIREN INR MLP — numpy-float32 emulation, packed-fp32.
// R9 (PASS 435.4us): L0/L1 numpy-exact tree+poly sin, L2/L3 fma-chain, magic-bit sin.
// R10 (PASS 429.8us): R9 verbatim, counters captured: VALUBusy 88.9%, MfmaUtil 0,
//  HBM 2%, 0 bank conflicts, VGPR 52. => VALU-issue-bound at ~1.8GHz sustained.
//  Op census: sins = 49% of issue cycles; L2's 20 sins = 16.4%.
// R11: L2 sins -> hardware v_sin_f32 (quarter-rate, SEPARATE trans pipe).
//  Error budget: L2 is the LAST sine layer; perturbations amplify only through
//  L3 linear (x~4.5), not the 90x/sine-layer chaos. Cody-Waite 2pi reduction
//  (numpy pi/2 triple-constant x4 = exact exponent shift) + v_sin in revolutions:
//  abs err ~2e-6 -> delta_out ~2e-5 vs absmax 0.0127. L0/L1 stay bit-stable poly.
//  Predicted: dur ~390us (-9%), absmax unchanged +-0.001.

typedef float v2f __attribute__((ext_vector_type(2)));

static constexpr int PW = 921;
static constexpr float MAGIC = 12582912.0f;   // 1.5 * 2^23

__device__ __forceinline__ v2f fma2(v2f a, v2f b, v2f c) {
    return __builtin_elementwise_fma(a, b, c);
}
__device__ __forceinline__ v2f splat2(float x) { v2f r; r.x = x; r.y = x; return r; }

// numpy SIMD f32 sin, 2 points packed (bit-exact config verified in R8).
__device__ __forceinline__ v2f np_sinf2(v2f x) {
#pragma clang fp contract(off)
    v2f t = x * splat2(0x1.45f306p-1f);
    v2f qf; qf.x = __builtin_rintf(t.x); qf.y = __builtin_rintf(t.y);
    const unsigned mx = __builtin_bit_cast(unsigned, __fadd_rn(qf.x, MAGIC));
    const unsigned my = __builtin_bit_cast(unsigned, __fadd_rn(qf.y, MAGIC));
    v2f r = fma2(qf, splat2(-0x1.921fb0p+0f), x);
    r = fma2(qf, splat2(-0x1.5110b4p-22f), r);
    r = fma2(qf, splat2(-0x1.846988p-48f), r);
    v2f r2 = r * r;
    v2f ys = fma2(splat2(0x1.5e9e9cp-19f), r2, splat2(-0x1.a06bbap-13f));
    ys = fma2(ys, r2, splat2(0x1.11119ap-7f));
    ys = fma2(ys, r2, splat2(-0x1.555556p-3f));
    ys = ys * r2;
    ys = fma2(ys, r, r);
    v2f yc = fma2(splat2(0x1.98e616p-16f), r2, splat2(-0x1.6c06dcp-10f));
    yc = fma2(yc, r2, splat2(0x1.55553cp-5f));
    yc = fma2(yc, r2, splat2(-0.5f));
    yc = fma2(yc, r2, splat2(1.0f));
    float rx = (mx & 1u) ? yc.x : ys.x;
    float ry = (my & 1u) ? yc.y : ys.y;
    const unsigned sx = (mx & 2u) << 30;   // q&2 -> sign bit
    const unsigned sy = (my & 2u) << 30;
    v2f res;
    res.x = __builtin_bit_cast(float, __builtin_bit_cast(unsigned, rx) ^ sx);
    res.y = __builtin_bit_cast(float, __builtin_bit_cast(unsigned, ry) ^ sy);
    return res;
}

// Hardware sin for the LAST sine layer only (L2): Cody-Waite reduce by 2pi
// (numpy pi/2 triple x4 — exact exponent shift), then v_sin_f32 (revolutions).
// Separate quarter-rate trans pipe: execution overlaps other waves' VALU issue.
__device__ __forceinline__ v2f hw_sin2(v2f x) {
#pragma clang fp contract(off)
    v2f t = x * splat2(0x1.45f306p-3f);               // x * 1/(2pi)
    v2f qf; qf.x = __builtin_rintf(t.x); qf.y = __builtin_rintf(t.y);
    v2f r = fma2(qf, splat2(-0x1.921fb0p+2f), x);     // 2pi hi
    r = fma2(qf, splat2(-0x1.5110b4p-20f), r);        // 2pi mid
    r = fma2(qf, splat2(-0x1.846988p-46f), r);        // 2pi lo
    v2f u = r * splat2(0x1.45f306p-3f);               // revolutions in [-0.5,0.5]
    v2f res;
    res.x = __builtin_amdgcn_sinf(u.x);
    res.y = __builtin_amdgcn_sinf(u.y);
    return res;
}

// numpy einsum contig_contig_outstride0_two tree (exact) — L1.
__device__ __forceinline__ v2f np_dot20_2(const float* __restrict__ w,
                                          const v2f* h) {
#pragma clang fp contract(off)
    v2f s[4];
#pragma unroll
    for (int j = 0; j < 4; ++j) {
        v2f p0  = h[j]      * splat2(w[j]);
        v2f p4  = h[4 + j]  * splat2(w[4 + j]);
        v2f p8  = h[8 + j]  * splat2(w[8 + j]);
        v2f p12 = h[12 + j] * splat2(w[12 + j]);
        v2f p16 = h[16 + j] * splat2(w[16 + j]);
        v2f t = p8 + p12;
        t = p4 + t;
        t = p0 + t;
        s[j] = p16 + t;
    }
    return (s[0] + s[1]) + (s[2] + s[3]);
}

// FMA-chain dot (bias-initialized) — L2/L3 only (bounded amplification).
__device__ __forceinline__ v2f fma_dot20(const float* __restrict__ w,
                                         const v2f* h, float bias) {
#pragma clang fp contract(off)
    v2f acc = splat2(bias);
#pragma unroll
    for (int i = 0; i < 20; ++i)
        acc = fma2(splat2(w[i]), h[i], acc);
    return acc;
}

__global__ void __launch_bounds__(256)
siren_mlp(const float* __restrict__ coords,
          const float* __restrict__ weights,
          float* __restrict__ out, int N)
{
#pragma clang fp contract(off)
    const int b = blockIdx.y;
    const float* __restrict__ w = weights + b * PW;  // wave-uniform -> s_load
    const int n0 = blockIdx.x * 512 + threadIdx.x;
    const int n1 = n0 + 256;
    const size_t base = (size_t)b * N;

    const float2* __restrict__ cp = (const float2*)coords;
    const float2 c0 = cp[base + n0];
    const float2 c1 = cp[base + n1];
    v2f X; X.x = c0.x; X.y = c1.x;
    v2f Y; Y.x = c0.y; Y.y = c1.y;

    v2f h[20], g[20];

    // ---- layer 0: 2 -> 20. (x*w0)+(y*w1), +b, *20 — numpy-exact, no fma.
#pragma unroll
    for (int o = 0; o < 20; ++o) {
        v2f z = (X * splat2(w[2 * o])) + (Y * splat2(w[2 * o + 1]));
        z = z + splat2(w[40 + o]);
        h[o] = np_sinf2(splat2(20.0f) * z);
    }

    // ---- layer 1: 20 -> 20 — numpy-exact tree + poly sin (bit-stable).
#pragma unroll
    for (int o = 0; o < 20; ++o) {
        v2f z = np_dot20_2(w + 60 + 20 * o, h) + splat2(w[460 + o]);
        g[o] = np_sinf2(splat2(20.0f) * z);
    }

    // ---- layer 2: 20 -> 20 — fma chain + HW sin (last sine layer, amp ~4.5x).
#pragma unroll
    for (int o = 0; o < 20; ++o) {
        v2f z = fma_dot20(w + 480 + 20 * o, g, w[880 + o]);
        h[o] = hw_sin2(splat2(20.0f) * z);
    }

    // ---- layer 3: 20 -> 1, clip[0,1] — fma chain, packed clamp.
    {
        v2f z = fma_dot20(w + 900, h, w[920]);
        z = __builtin_elementwise_max(z, splat2(0.0f));
        z = __builtin_elementwise_min(z, splat2(1.0f));
        out[base + n0] = z.x;
        out[base + n1] = z.y;
    }
}

extern "C" void kernel_launch(void* const* d_in, const int* in_sizes, int n_in,
                              void* d_out, int out_size, void* d_ws, size_t ws_size,
                              hipStream_t stream) {
    const float* coords  = (const float*)d_in[0];
    const float* weights = (const float*)d_in[1];
    float* out = (float*)d_out;

    const int B = in_sizes[1] / PW;            // 128
    const int N = in_sizes[0] / (2 * B);       // 65536

    dim3 grid(N / 512, B);
    siren_mlp<<<grid, dim3(256), 0, stream>>>(coords, weights, out, N);
}

// Round 5
// 349.099 us; speedup vs baseline: 1.2457x; 1.1483x over previous
//
#include <hip/hip_runtime.h>

// SIREN INR MLP — numpy-float32 emulation, fp32 scalar VALU.
// R9  (PASS 435.4us): L0/L1 numpy-exact tree+poly sin, L2/L3 fma-chain, magic-bit sin.
// R10 (PASS 429.8us): counters: VALUBusy 88.9%, MfmaUtil 0, HBM 2%, VGPR 52.
//   => ~5360 scalar VALU ops, issue-bound at ~1.8GHz sustained.
// R11 (PASS 400.9us, absmax BIT-IDENTICAL 0.01269531): L2 sins -> Cody-Waite
//   + v_sin_f32 (separate quarter-rate trans pipe). -11%. Error-model calibrated:
//   predicted ~e-5 output delta, observed none.
// R12 (FAIL, out=NaN->clip->0): v_pk_{fma,mul,add}_f32 inline-asm probe. Packed
//   FP32 is broken/absent on gfx950 — spec arithmetic agrees: 157.3TF =
//   256CUx128lanesx2FLOPx2.4GHz EXACTLY scalar, no packing factor (CDNA4 cut
//   the dual-issue f32 datapath, cf. FP64=1/2 FP32). DEAD END, reverted.
// R13: extend the calibrated trans-pipe lever within error budget:
//   - L1 sins -> Cody-Waite + v_sin (ampl to out ~405x ulp-level => ~1.5e-4).
//   - L2 sins -> raw v_fract+v_sin, drop Cody-Waite (|u|<=48 rev; u-rounding
//     1.8e-5 * amp 4.5 => ~1.5e-4).
//   - L1 DOT stays numpy-exact tree (fma-chain diff ~7e-3 out — too risky).
//   - L0 stays bit-exact poly (amp 36000x).
//   Saves ~720 of 4680 issue slots. Predict: ~325us dispatch, absmax 0.0127+-5e-4.
// R14: resubmit of R13 verbatim — R13's bench was an infra failure (container
//   acquisition failed twice), kernel never ran. Prediction stands.

typedef float v2f __attribute__((ext_vector_type(2)));

static constexpr int PW = 921;
static constexpr float MAGIC = 12582912.0f;   // 1.5 * 2^23

__device__ __forceinline__ v2f fma2(v2f a, v2f b, v2f c) {
    return __builtin_elementwise_fma(a, b, c);
}
__device__ __forceinline__ v2f splat2(float x) { v2f r; r.x = x; r.y = x; return r; }

// numpy SIMD f32 sin (bit-exact, magic-bit quadrant) — L0 ONLY.
__device__ __forceinline__ v2f np_sinf2(v2f x) {
#pragma clang fp contract(off)
    v2f t = x * splat2(0x1.45f306p-1f);
    v2f qf; qf.x = __builtin_rintf(t.x); qf.y = __builtin_rintf(t.y);
    const unsigned mx = __builtin_bit_cast(unsigned, __fadd_rn(qf.x, MAGIC));
    const unsigned my = __builtin_bit_cast(unsigned, __fadd_rn(qf.y, MAGIC));
    v2f r = fma2(qf, splat2(-0x1.921fb0p+0f), x);
    r = fma2(qf, splat2(-0x1.5110b4p-22f), r);
    r = fma2(qf, splat2(-0x1.846988p-48f), r);
    v2f r2 = r * r;
    v2f ys = fma2(splat2(0x1.5e9e9cp-19f), r2, splat2(-0x1.a06bbap-13f));
    ys = fma2(ys, r2, splat2(0x1.11119ap-7f));
    ys = fma2(ys, r2, splat2(-0x1.555556p-3f));
    ys = ys * r2;
    ys = fma2(ys, r, r);
    v2f yc = fma2(splat2(0x1.98e616p-16f), r2, splat2(-0x1.6c06dcp-10f));
    yc = fma2(yc, r2, splat2(0x1.55553cp-5f));
    yc = fma2(yc, r2, splat2(-0.5f));
    yc = fma2(yc, r2, splat2(1.0f));
    float rx = (mx & 1u) ? yc.x : ys.x;
    float ry = (my & 1u) ? yc.y : ys.y;
    const unsigned sx = (mx & 2u) << 30;   // q&2 -> sign bit
    const unsigned sy = (my & 2u) << 30;
    v2f res;
    res.x = __builtin_bit_cast(float, __builtin_bit_cast(unsigned, rx) ^ sx);
    res.y = __builtin_bit_cast(float, __builtin_bit_cast(unsigned, ry) ^ sy);
    return res;
}

// HW sin w/ Cody-Waite 2pi pre-reduction (abs-accurate for |z| up to ~1e4) — L1.
// Residual kept in radians at full abs precision, then scaled to revolutions.
__device__ __forceinline__ v2f hw_sin2(v2f x) {
#pragma clang fp contract(off)
    v2f t = x * splat2(0x1.45f306p-3f);               // x * 1/(2pi)
    v2f qf; qf.x = __builtin_rintf(t.x); qf.y = __builtin_rintf(t.y);
    v2f r = fma2(qf, splat2(-0x1.921fb0p+2f), x);     // 2pi hi
    r = fma2(qf, splat2(-0x1.5110b4p-20f), r);        // 2pi mid
    r = fma2(qf, splat2(-0x1.846988p-46f), r);        // 2pi lo
    v2f u = r * splat2(0x1.45f306p-3f);               // revolutions in [-0.5,0.5]
    v2f res;
    res.x = __builtin_amdgcn_sinf(u.x);
    res.y = __builtin_amdgcn_sinf(u.y);
    return res;
}

// Raw HW sin (no pre-reduction): u = z/(2pi), fract (exact), v_sin — L2 ONLY.
// u-rounding err <= |u|*2^-24 rev ~ 1.8e-5 rad at |z|~300; amp to out ~4.5x.
__device__ __forceinline__ v2f hw_sin_raw2(v2f x) {
#pragma clang fp contract(off)
    v2f u = x * splat2(0x1.45f306p-3f);               // revolutions
    v2f res;
    res.x = __builtin_amdgcn_sinf(__builtin_amdgcn_fractf(u.x));
    res.y = __builtin_amdgcn_sinf(__builtin_amdgcn_fractf(u.y));
    return res;
}

// numpy einsum contig_contig_outstride0_two tree (exact) — L1.
__device__ __forceinline__ v2f np_dot20_2(const float* __restrict__ w,
                                          const v2f* h) {
#pragma clang fp contract(off)
    v2f s[4];
#pragma unroll
    for (int j = 0; j < 4; ++j) {
        v2f p0  = h[j]      * splat2(w[j]);
        v2f p4  = h[4 + j]  * splat2(w[4 + j]);
        v2f p8  = h[8 + j]  * splat2(w[8 + j]);
        v2f p12 = h[12 + j] * splat2(w[12 + j]);
        v2f p16 = h[16 + j] * splat2(w[16 + j]);
        v2f t = p8 + p12;
        t = p4 + t;
        t = p0 + t;
        s[j] = p16 + t;
    }
    return (s[0] + s[1]) + (s[2] + s[3]);
}

// FMA-chain dot (bias-initialized) — L2/L3 only (bounded amplification).
__device__ __forceinline__ v2f fma_dot20(const float* __restrict__ w,
                                         const v2f* h, float bias) {
#pragma clang fp contract(off)
    v2f acc = splat2(bias);
#pragma unroll
    for (int i = 0; i < 20; ++i)
        acc = fma2(splat2(w[i]), h[i], acc);
    return acc;
}

__global__ void __launch_bounds__(256)
siren_mlp(const float* __restrict__ coords,
          const float* __restrict__ weights,
          float* __restrict__ out, int N)
{
#pragma clang fp contract(off)
    const int b = blockIdx.y;
    const float* __restrict__ w = weights + b * PW;  // wave-uniform -> s_load
    const int n0 = blockIdx.x * 512 + threadIdx.x;
    const int n1 = n0 + 256;
    const size_t base = (size_t)b * N;

    const float2* __restrict__ cp = (const float2*)coords;
    const float2 c0 = cp[base + n0];
    const float2 c1 = cp[base + n1];
    v2f X; X.x = c0.x; X.y = c1.x;
    v2f Y; Y.x = c0.y; Y.y = c1.y;

    v2f h[20], g[20];

    // ---- layer 0: 2 -> 20. (x*w0)+(y*w1), +b, *20 — numpy-exact, no fma.
#pragma unroll
    for (int o = 0; o < 20; ++o) {
        v2f z = (X * splat2(w[2 * o])) + (Y * splat2(w[2 * o + 1]));
        z = z + splat2(w[40 + o]);
        h[o] = np_sinf2(splat2(20.0f) * z);
    }

    // ---- layer 1: 20 -> 20 — numpy-exact tree dot + HW sin (CW-reduced).
#pragma unroll
    for (int o = 0; o < 20; ++o) {
        v2f z = np_dot20_2(w + 60 + 20 * o, h) + splat2(w[460 + o]);
        g[o] = hw_sin2(splat2(20.0f) * z);
    }

    // ---- layer 2: 20 -> 20 — fma chain + raw HW sin (last sine layer).
#pragma unroll
    for (int o = 0; o < 20; ++o) {
        v2f z = fma_dot20(w + 480 + 20 * o, g, w[880 + o]);
        h[o] = hw_sin_raw2(splat2(20.0f) * z);
    }

    // ---- layer 3: 20 -> 1, clip[0,1] — fma chain, packed clamp.
    {
        v2f z = fma_dot20(w + 900, h, w[920]);
        z = __builtin_elementwise_max(z, splat2(0.0f));
        z = __builtin_elementwise_min(z, splat2(1.0f));
        out[base + n0] = z.x;
        out[base + n1] = z.y;
    }
}

extern "C" void kernel_launch(void* const* d_in, const int* in_sizes, int n_in,
                              void* d_out, int out_size, void* d_ws, size_t ws_size,
                              hipStream_t stream) {
    const float* coords  = (const float*)d_in[0];
    const float* weights = (const float*)d_in[1];
    float* out = (float*)d_out;

    const int B = in_sizes[1] / PW;            // 128
    const int N = in_sizes[0] / (2 * B);       // 65536

    dim3 grid(N / 512, B);
    siren_mlp<<<grid, dim3(256), 0, stream>>>(coords, weights, out, N);
}

// Round 6
// 316.282 us; speedup vs baseline: 1.3749x; 1.1038x over previous
//
#include <hip/hip_runtime.h>

// SIREN INR MLP — numpy-float32 emulation, fp32 scalar VALU.
// R9  (PASS 435.4us): L0/L1 numpy-exact tree+poly sin, L2/L3 fma-chain, magic-bit sin.
// R10 (PASS 429.8us): VALUBusy 88.9%, MfmaUtil 0, HBM 2%, VGPR 52 => issue-bound,
//   ~5360 scalar VALU ops/thread at ~1.8GHz sustained.
// R11 (PASS 400.9us, absmax BIT-IDENTICAL): L2 sins -> CW + v_sin_f32 (trans pipe).
// R12 (FAIL NaN): v_pk_*_f32 probe — packed FP32 broken/absent on gfx950. Reverted.
// R13/R14 (PASS 349us harness / 317.5us dispatch, absmax BIT-IDENTICAL 0.01269531):
//   L1 sins -> CW + v_sin; L2 sins -> raw fract + v_sin. VGPR 44, occ 55%,
//   VALUBusy 87.8%. Error model confirmed conservative (clip-saturated max point).
// R15: LAST sin conversion — L0 poly -> CW + v_sin (saves 600 of ~4050 ops, -15%).
//   L0 has the largest amplification (RMS amp h0->out ~1.3e4): CW keeps angle err
//   at ~3e-7 rad (= poly path floor), so added error == v_sin eval error vs poly.
//   If v_sin ~1ulp: delta_out ~1.6e-3 RMS -> PASS (absmax drifts <1e-3).
//   If v_sin ~2^-21: delta_out tail ~6e-3 vs 7.3e-3 headroom -> marginal/FAIL.
//   This round doubles as the v_sin accuracy measurement. FAIL => revert to R14
//   (317us) and declare roofline. L1 tree-dot fma-chaining PERMANENTLY REJECTED:
//   recomputed delta_out ~0.012 RMS — exceeds headroom, not just risky.

typedef float v2f __attribute__((ext_vector_type(2)));

static constexpr int PW = 921;

__device__ __forceinline__ v2f fma2(v2f a, v2f b, v2f c) {
    return __builtin_elementwise_fma(a, b, c);
}
__device__ __forceinline__ v2f splat2(float x) { v2f r; r.x = x; r.y = x; return r; }

// HW sin w/ Cody-Waite 2pi pre-reduction — L0 and L1.
// Residual in radians exact to ~3e-7 abs, scaled to revolutions for v_sin.
__device__ __forceinline__ v2f hw_sin2(v2f x) {
#pragma clang fp contract(off)
    v2f t = x * splat2(0x1.45f306p-3f);               // x * 1/(2pi)
    v2f qf; qf.x = __builtin_rintf(t.x); qf.y = __builtin_rintf(t.y);
    v2f r = fma2(qf, splat2(-0x1.921fb0p+2f), x);     // 2pi hi
    r = fma2(qf, splat2(-0x1.5110b4p-20f), r);        // 2pi mid
    r = fma2(qf, splat2(-0x1.846988p-46f), r);        // 2pi lo
    v2f u = r * splat2(0x1.45f306p-3f);               // revolutions in [-0.5,0.5]
    v2f res;
    res.x = __builtin_amdgcn_sinf(u.x);
    res.y = __builtin_amdgcn_sinf(u.y);
    return res;
}

// Raw HW sin (no pre-reduction): u = z/(2pi), fract (exact), v_sin — L2 ONLY.
// u-rounding err <= |u|*2^-24 rev ~ 1.8e-5 rad at |z|~300; amp to out ~4.5x.
__device__ __forceinline__ v2f hw_sin_raw2(v2f x) {
#pragma clang fp contract(off)
    v2f u = x * splat2(0x1.45f306p-3f);               // revolutions
    v2f res;
    res.x = __builtin_amdgcn_sinf(__builtin_amdgcn_fractf(u.x));
    res.y = __builtin_amdgcn_sinf(__builtin_amdgcn_fractf(u.y));
    return res;
}

// numpy einsum contig_contig_outstride0_two tree (exact) — L1.
__device__ __forceinline__ v2f np_dot20_2(const float* __restrict__ w,
                                          const v2f* h) {
#pragma clang fp contract(off)
    v2f s[4];
#pragma unroll
    for (int j = 0; j < 4; ++j) {
        v2f p0  = h[j]      * splat2(w[j]);
        v2f p4  = h[4 + j]  * splat2(w[4 + j]);
        v2f p8  = h[8 + j]  * splat2(w[8 + j]);
        v2f p12 = h[12 + j] * splat2(w[12 + j]);
        v2f p16 = h[16 + j] * splat2(w[16 + j]);
        v2f t = p8 + p12;
        t = p4 + t;
        t = p0 + t;
        s[j] = p16 + t;
    }
    return (s[0] + s[1]) + (s[2] + s[3]);
}

// FMA-chain dot (bias-initialized) — L2/L3 only (bounded amplification).
__device__ __forceinline__ v2f fma_dot20(const float* __restrict__ w,
                                         const v2f* h, float bias) {
#pragma clang fp contract(off)
    v2f acc = splat2(bias);
#pragma unroll
    for (int i = 0; i < 20; ++i)
        acc = fma2(splat2(w[i]), h[i], acc);
    return acc;
}

__global__ void __launch_bounds__(256)
siren_mlp(const float* __restrict__ coords,
          const float* __restrict__ weights,
          float* __restrict__ out, int N)
{
#pragma clang fp contract(off)
    const int b = blockIdx.y;
    const float* __restrict__ w = weights + b * PW;  // wave-uniform -> s_load
    const int n0 = blockIdx.x * 512 + threadIdx.x;
    const int n1 = n0 + 256;
    const size_t base = (size_t)b * N;

    const float2* __restrict__ cp = (const float2*)coords;
    const float2 c0 = cp[base + n0];
    const float2 c1 = cp[base + n1];
    v2f X; X.x = c0.x; X.y = c1.x;
    v2f Y; Y.x = c0.y; Y.y = c1.y;

    v2f h[20], g[20];

    // ---- layer 0: 2 -> 20. (x*w0)+(y*w1), +b, *20 — numpy-exact dot, no fma.
    //      sin via CW + v_sin (R15 change — angle err floor ~3e-7 rad).
#pragma unroll
    for (int o = 0; o < 20; ++o) {
        v2f z = (X * splat2(w[2 * o])) + (Y * splat2(w[2 * o + 1]));
        z = z + splat2(w[40 + o]);
        h[o] = hw_sin2(splat2(20.0f) * z);
    }

    // ---- layer 1: 20 -> 20 — numpy-exact tree dot + HW sin (CW-reduced).
#pragma unroll
    for (int o = 0; o < 20; ++o) {
        v2f z = np_dot20_2(w + 60 + 20 * o, h) + splat2(w[460 + o]);
        g[o] = hw_sin2(splat2(20.0f) * z);
    }

    // ---- layer 2: 20 -> 20 — fma chain + raw HW sin (last sine layer).
#pragma unroll
    for (int o = 0; o < 20; ++o) {
        v2f z = fma_dot20(w + 480 + 20 * o, g, w[880 + o]);
        h[o] = hw_sin_raw2(splat2(20.0f) * z);
    }

    // ---- layer 3: 20 -> 1, clip[0,1] — fma chain, packed clamp.
    {
        v2f z = fma_dot20(w + 900, h, w[920]);
        z = __builtin_elementwise_max(z, splat2(0.0f));
        z = __builtin_elementwise_min(z, splat2(1.0f));
        out[base + n0] = z.x;
        out[base + n1] = z.y;
    }
}

extern "C" void kernel_launch(void* const* d_in, const int* in_sizes, int n_in,
                              void* d_out, int out_size, void* d_ws, size_t ws_size,
                              hipStream_t stream) {
    const float* coords  = (const float*)d_in[0];
    const float* weights = (const float*)d_in[1];
    float* out = (float*)d_out;

    const int B = in_sizes[1] / PW;            // 128
    const int N = in_sizes[0] / (2 * B);       // 65536

    dim3 grid(N / 512, B);
    siren_mlp<<<grid, dim3(256), 0, stream>>>(coords, weights, out, N);
}

// Round 7
// 309.234 us; speedup vs baseline: 1.4063x; 1.0228x over previous
//
#include <hip/hip_runtime.h>

// SIREN INR MLP — numpy-float32 emulation, fp32 scalar VALU.
// R9  (PASS 435.4us): L0/L1 numpy-exact tree+poly sin, L2/L3 fma-chain, magic-bit sin.
// R10 (PASS 429.8us): VALUBusy 88.9%, MfmaUtil 0, HBM 2%, VGPR 52 => issue-bound,
//   ~5360 scalar VALU ops/thread at ~1.8GHz sustained.
// R11 (PASS 400.9us, absmax BIT-IDENTICAL): L2 sins -> CW + v_sin_f32 (trans pipe).
// R12 (FAIL NaN): v_pk_*_f32 probe — packed FP32 broken/absent on gfx950. Reverted.
// R13/R14 (PASS 317.5us dispatch, absmax BIT-IDENTICAL): L1 -> CW+v_sin, L2 -> raw.
// R15 (PASS 316.3us harness / 277.4us dispatch, absmax 0.01757812): L0 -> CW+v_sin.
//   v_sin eval err back-solved ~4e-7 (2-3 ulp); consumed 5e-3 headroom at L0's
//   1.3e4 amp. HEADROOM NOW 0.0024: L1-prescale (~3e-3), L1-fma-chain (0.012),
//   any L0 change (0.026) all PERMANENTLY REJECTED.
// R16: last certifiably-safe trims (-120 of ~3330 ops = -3.6%):
//   (a) drop CW lo-term (q*2pi_lo <= 7e-13 << 1/2 ulp(r) -> r unchanged except
//       measure-zero boundaries, ~0.16 expected occurrences, each <=7e-4);
//   (b) L2: fold omega into sin scale u = d*RN(10/pi), 1 rounding vs 2
//       (~1ulp angle = 4e-7 rad x amp 4.5 = 2e-6 out);
//   (c) L0 keeps materialized 20*z (folding = 0.026 shift, FAIL).
//   Predict: 267-270us dispatch, absmax 0.0176 +- 2e-4. If on-model: remaining
//   is only ~13% issue-idle w/ no safe lever -> roofline next round.

typedef float v2f __attribute__((ext_vector_type(2)));

static constexpr int PW = 921;

__device__ __forceinline__ v2f fma2(v2f a, v2f b, v2f c) {
    return __builtin_elementwise_fma(a, b, c);
}
__device__ __forceinline__ v2f splat2(float x) { v2f r; r.x = x; r.y = x; return r; }

// HW sin w/ 2-term Cody-Waite 2pi pre-reduction — L0 and L1.
// Residual r = theta - q*(2pi_hi+2pi_mid); dropped lo-term contributes
// q*2.2e-14 <= 7e-13 rad << 1/2 ulp(r): provably identical rounding a.e.
__device__ __forceinline__ v2f hw_sin2(v2f x) {
#pragma clang fp contract(off)
    v2f t = x * splat2(0x1.45f306p-3f);               // x * 1/(2pi)
    v2f qf; qf.x = __builtin_rintf(t.x); qf.y = __builtin_rintf(t.y);
    v2f r = fma2(qf, splat2(-0x1.921fb0p+2f), x);     // 2pi hi
    r = fma2(qf, splat2(-0x1.5110b4p-20f), r);        // 2pi mid
    v2f u = r * splat2(0x1.45f306p-3f);               // revolutions in [-0.5,0.5]
    v2f res;
    res.x = __builtin_amdgcn_sinf(u.x);
    res.y = __builtin_amdgcn_sinf(u.y);
    return res;
}

// Raw HW sin with folded omega — L2 ONLY. Input d is the PRE-omega dot value;
// u = d * RN(20/(2pi)) in one rounding (vs two before: ~1ulp angle diff,
// x4.5 amp -> ~2e-6 out). fract exact; |u| <= ~48 rev.
__device__ __forceinline__ v2f hw_sin_w20_2(v2f d) {
#pragma clang fp contract(off)
    v2f u = d * splat2(3.1830988618379067f);          // 20/(2pi) = 10/pi
    v2f res;
    res.x = __builtin_amdgcn_sinf(__builtin_amdgcn_fractf(u.x));
    res.y = __builtin_amdgcn_sinf(__builtin_amdgcn_fractf(u.y));
    return res;
}

// numpy einsum contig_contig_outstride0_two tree (exact) — L1.
__device__ __forceinline__ v2f np_dot20_2(const float* __restrict__ w,
                                          const v2f* h) {
#pragma clang fp contract(off)
    v2f s[4];
#pragma unroll
    for (int j = 0; j < 4; ++j) {
        v2f p0  = h[j]      * splat2(w[j]);
        v2f p4  = h[4 + j]  * splat2(w[4 + j]);
        v2f p8  = h[8 + j]  * splat2(w[8 + j]);
        v2f p12 = h[12 + j] * splat2(w[12 + j]);
        v2f p16 = h[16 + j] * splat2(w[16 + j]);
        v2f t = p8 + p12;
        t = p4 + t;
        t = p0 + t;
        s[j] = p16 + t;
    }
    return (s[0] + s[1]) + (s[2] + s[3]);
}

// FMA-chain dot (bias-initialized) — L2/L3 only (bounded amplification).
__device__ __forceinline__ v2f fma_dot20(const float* __restrict__ w,
                                         const v2f* h, float bias) {
#pragma clang fp contract(off)
    v2f acc = splat2(bias);
#pragma unroll
    for (int i = 0; i < 20; ++i)
        acc = fma2(splat2(w[i]), h[i], acc);
    return acc;
}

__global__ void __launch_bounds__(256)
siren_mlp(const float* __restrict__ coords,
          const float* __restrict__ weights,
          float* __restrict__ out, int N)
{
#pragma clang fp contract(off)
    const int b = blockIdx.y;
    const float* __restrict__ w = weights + b * PW;  // wave-uniform -> s_load
    const int n0 = blockIdx.x * 512 + threadIdx.x;
    const int n1 = n0 + 256;
    const size_t base = (size_t)b * N;

    const float2* __restrict__ cp = (const float2*)coords;
    const float2 c0 = cp[base + n0];
    const float2 c1 = cp[base + n1];
    v2f X; X.x = c0.x; X.y = c1.x;
    v2f Y; Y.x = c0.y; Y.y = c1.y;

    v2f h[20], g[20];

    // ---- layer 0: 2 -> 20. (x*w0)+(y*w1), +b — numpy-exact dot, no fma.
    //      Angle 20*z MATERIALIZED (folding into sin scale = 0.026 fail).
#pragma unroll
    for (int o = 0; o < 20; ++o) {
        v2f z = (X * splat2(w[2 * o])) + (Y * splat2(w[2 * o + 1]));
        z = z + splat2(w[40 + o]);
        h[o] = hw_sin2(splat2(20.0f) * z);
    }

    // ---- layer 1: 20 -> 20 — numpy-exact tree dot + HW sin (2-term CW).
#pragma unroll
    for (int o = 0; o < 20; ++o) {
        v2f z = np_dot20_2(w + 60 + 20 * o, h) + splat2(w[460 + o]);
        g[o] = hw_sin2(splat2(20.0f) * z);
    }

    // ---- layer 2: 20 -> 20 — fma chain + folded-omega raw HW sin.
#pragma unroll
    for (int o = 0; o < 20; ++o) {
        v2f d = fma_dot20(w + 480 + 20 * o, g, w[880 + o]);
        h[o] = hw_sin_w20_2(d);
    }

    // ---- layer 3: 20 -> 1, clip[0,1] — fma chain, packed clamp.
    {
        v2f z = fma_dot20(w + 900, h, w[920]);
        z = __builtin_elementwise_max(z, splat2(0.0f));
        z = __builtin_elementwise_min(z, splat2(1.0f));
        out[base + n0] = z.x;
        out[base + n1] = z.y;
    }
}

extern "C" void kernel_launch(void* const* d_in, const int* in_sizes, int n_in,
                              void* d_out, int out_size, void* d_ws, size_t ws_size,
                              hipStream_t stream) {
    const float* coords  = (const float*)d_in[0];
    const float* weights = (const float*)d_in[1];
    float* out = (float*)d_out;

    const int B = in_sizes[1] / PW;            // 128
    const int N = in_sizes[0] / (2 * B);       // 65536

    dim3 grid(N / 512, B);
    siren_mlp<<<grid, dim3(256), 0, stream>>>(coords, weights, out, N);
}